// Round 3
// baseline (854.900 us; speedup 1.0000x reference)
//
#include <hip/hip_runtime.h>
#include <hip/hip_bf16.h>
#include <math.h>

// Problem constants (from reference)
#define N_NODES 10000
#define N_EDGES 80000
#define N_GRAPHS 64
#define NH 4
#define HD 512
#define HDTOT 2048   // NH*HD
#define EMB 768
#define HFEAT 512
#define MAXDEG 512   // LDS softmax-weight capacity per node

typedef _Float16 half8 __attribute__((ext_vector_type(8)));
typedef _Float16 half4 __attribute__((ext_vector_type(4)));
typedef float f32x4 __attribute__((ext_vector_type(4)));

// Async global->LDS, 16B per lane. LDS dest = wave-uniform base + lane*16;
// the GLOBAL SOURCE ADDRESS IS PER-LANE. Lanes fetch their row's K-granules
// in XOR-permuted order, so the DMA lands a swizzled LDS image from a PLAIN
// row-major global plane. Zero VALU repack.
__device__ __forceinline__ void gload_lds16(const void* g, void* l) {
  __builtin_amdgcn_global_load_lds(
      (const __attribute__((address_space(1))) unsigned int*)g,
      (__attribute__((address_space(3))) unsigned int*)l, 16, 0, 0);
}

// ---------------------------------------------------------------------------
// Plain-fp16 MFMA GEMM (m97-structure): C = act(A @ B + bias), fp16 planes.
// R2 post-mortem: the 256^2 counted-vmcnt pipeline measured 697 TF at full
// machine vs this kernel's 763 (R1's "867 per-CU" was round-2 tailwind).
// Coarse counted-vmcnt without the true 8-phase interleave is null-to-negative
// (guide m196), so the fc GEMMs are REVERTED to this proven path.
// Tile BM x 128, 256 threads. K%64==0.
// ---------------------------------------------------------------------------
template <int BM>
__global__ __launch_bounds__(256) void gemm_f16_kernel(
    const _Float16* __restrict__ A, const _Float16* __restrict__ BT,
    const float* __restrict__ bias, _Float16* __restrict__ C,
    int M, int N, int K, int act) {
  constexpr int WR = (BM == 128) ? 2 : 1;  // wave grid rows
  constexpr int WC = 4 / WR;               // wave grid cols
  constexpr int MI = (BM / WR) / 16;       // m-frags per wave (4)
  constexpr int NI = (128 / WC) / 16;      // n-frags per wave (4 or 2)
  constexpr int NW = NI * 16;              // wave n-width (64 or 32)
  constexpr int CS = NW + 4;               // epilogue scratch row stride
  constexpr int GPR = NW / 8;              // 16B granules per scratch row

  __shared__ _Float16 smem[(BM + 128) * 64];
  _Float16* As = smem;             // BM x 64 (swizzled image)
  _Float16* Bs = smem + BM * 64;   // 128 x 64 (swizzled image)

  const int bn = blockIdx.x * 128, bm = blockIdx.y * BM;
  const int t = threadIdx.x;
  const int lane = t & 63, wave = t >> 6;
  const int wr = wave / WC, wc = wave % WC;
  const int m0 = wr * (BM / WR), n0 = wc * NW;
  const int fr = lane & 15, fq = lane >> 4;

  f32x4 acc[MI][NI];
#pragma unroll
  for (int i = 0; i < MI; ++i)
#pragma unroll
    for (int j = 0; j < NI; ++j) acc[i][j] = (f32x4){0.f, 0.f, 0.f, 0.f};

  for (int k0 = 0; k0 < K; k0 += 64) {
    __syncthreads();  // protect LDS from previous iteration's readers
#pragma unroll
    for (int it = 0; it < BM / 32; ++it) {
      int gid = it * 256 + t;
      int r = gid >> 3;
      int q = (gid & 7) ^ (r & 7);  // fetch permuted granule
      int grow = bm + r;
      if (grow >= M) grow = M - 1;  // clamp; garbage masked in epilogue
      gload_lds16(A + (size_t)grow * K + k0 + q * 8,
                  &As[(it * 256 + wave * 64) * 8]);
    }
#pragma unroll
    for (int it = 0; it < 4; ++it) {
      int gid = it * 256 + t;
      int r = gid >> 3;
      int q = (gid & 7) ^ (r & 7);
      gload_lds16(BT + (size_t)(bn + r) * K + k0 + q * 8,
                  &Bs[(it * 256 + wave * 64) * 8]);
    }
    __syncthreads();

#pragma unroll
    for (int kk = 0; kk < 2; ++kk) {
      half8 af[MI], bf[NI];
#pragma unroll
      for (int mi = 0; mi < MI; ++mi) {
        int m = m0 + mi * 16 + fr;
        af[mi] = *(const half8*)&As[m * 64 + (((kk * 4 + fq) ^ (m & 7))) * 8];
      }
#pragma unroll
      for (int ni = 0; ni < NI; ++ni) {
        int n = n0 + ni * 16 + fr;
        bf[ni] = *(const half8*)&Bs[n * 64 + (((kk * 4 + fq) ^ (n & 7))) * 8];
      }
#pragma unroll
      for (int mi = 0; mi < MI; ++mi)
#pragma unroll
        for (int ni = 0; ni < NI; ++ni)
          acc[mi][ni] = __builtin_amdgcn_mfma_f32_16x16x32_f16(
              af[mi], bf[ni], acc[mi][ni], 0, 0, 0);
    }
  }
  __syncthreads();  // all K-loop LDS reads done; staging smem reusable
  _Float16* cs = smem + wave * 16 * CS;  // wave-private scratch (16 x CS)
#pragma unroll
  for (int mi = 0; mi < MI; ++mi) {
#pragma unroll
    for (int ni = 0; ni < NI; ++ni) {
      float bb = bias ? bias[bn + n0 + ni * 16 + fr] : 0.f;
#pragma unroll
      for (int j = 0; j < 4; ++j) {
        float v = acc[mi][ni][j] + bb;
        if (act == 1) v = v > 0.f ? v : expm1f(v);
        cs[(fq * 4 + j) * CS + ni * 16 + fr] = (_Float16)v;
      }
    }
#pragma unroll
    for (int i = 0; i < NW / 32; ++i) {
      int piece = i * 64 + lane;
      int r = piece / GPR, g = piece % GPR;
      int grow = bm + m0 + mi * 16 + r;
      if (grow < M) {
        half8 v = *(const half8*)&cs[r * CS + g * 8];
        *(half8*)&C[(size_t)grow * N + bn + n0 + g * 8] = v;
      }
    }
  }
}

// ---------------------------------------------------------------------------
// NEW (R3): fused 8-layer hidden MLP. One block = 32 rows; the 32x512 fp16
// activation tile stays in LDS across all 8 layers (XOR-granule swizzle,
// 2-way bank aliasing = free). Weights pre-converted to FRAG-MAJOR fp16
// (convert_fb_kernel) so each B-fragment is ONE contiguous 1-KB wave-
// coalesced load from L2 (512 KB/layer, L2-resident) — no B staging, no
// staging barriers. Per layer: 16 K-steps x {2 LDS A-frags + 8 streamed
// B-frags + 16 MFMA}; epilogue bias+ELU in regs, swizzled write-back.
// Replaces 8 gemm<64> launches + 8x20 MB of HBM activation traffic.
// Numeric path identical to gemm path: f32 acc, f32 bias+ELU, fp16 store.
// ---------------------------------------------------------------------------
#define HB 32  // rows per block

__global__ __launch_bounds__(256) void hidden8_kernel(
    const _Float16* __restrict__ in,   // (N_NODES,512) fp16
    const _Float16* __restrict__ FB,   // frag-major [8][16][32][64][8]
    const float* __restrict__ bh,      // (8,512) f32
    _Float16* __restrict__ outp) {     // (N_NODES,512) fp16
  __shared__ _Float16 IT[HB * 512];    // 32 KB swizzled activation tile
  const int bm = blockIdx.x * HB;
  const int t = threadIdx.x;
  const int lane = t & 63, wc = t >> 6;  // 4 waves, each owns 128 cols
  const int fr = lane & 15, fq = lane >> 4;

  // ---- stage input tile: coalesced global read, swizzled LDS write ----
#pragma unroll
  for (int k = 0; k < 8; ++k) {
    int gi = k * 256 + t;            // 2048 granules = 32 rows x 64
    int r = gi >> 6, g = gi & 63;
    int grow = bm + r;
    if (grow >= N_NODES) grow = N_NODES - 1;  // clamp; masked at final store
    half8 v = *(const half8*)&in[(size_t)grow * HFEAT + g * 8];
    *(half8*)&IT[r * HFEAT + ((g ^ (r & 7)) << 3)] = v;
  }
  __syncthreads();

#pragma unroll 1
  for (int l = 0; l < 8; ++l) {
    f32x4 acc[2][8];
#pragma unroll
    for (int mi = 0; mi < 2; ++mi)
#pragma unroll
      for (int ni = 0; ni < 8; ++ni) acc[mi][ni] = (f32x4){0.f, 0.f, 0.f, 0.f};

    const _Float16* fb = FB + (size_t)l * (16 * 32 * 512);
#pragma unroll 2
    for (int ks = 0; ks < 16; ++ks) {
      half8 af[2];
#pragma unroll
      for (int mi = 0; mi < 2; ++mi) {
        int m = mi * 16 + fr;
        af[mi] = *(const half8*)&IT[m * HFEAT + (((ks * 4 + fq) ^ (m & 7)) << 3)];
      }
      half8 bf[8];
#pragma unroll
      for (int ni = 0; ni < 8; ++ni)
        bf[ni] = *(const half8*)&fb[((size_t)ks * 32 + wc * 8 + ni) * 512 + lane * 8];
#pragma unroll
      for (int mi = 0; mi < 2; ++mi)
#pragma unroll
        for (int ni = 0; ni < 8; ++ni)
          acc[mi][ni] = __builtin_amdgcn_mfma_f32_16x16x32_f16(
              af[mi], bf[ni], acc[mi][ni], 0, 0, 0);
    }
    __syncthreads();  // all IT reads of this layer done
    // ---- bias + ELU, swizzled write-back into IT ----
#pragma unroll
    for (int mi = 0; mi < 2; ++mi)
#pragma unroll
      for (int ni = 0; ni < 8; ++ni) {
        int c = wc * 128 + ni * 16 + fr;
        float bb = bh[l * 512 + c];
#pragma unroll
        for (int j = 0; j < 4; ++j) {
          float v = acc[mi][ni][j] + bb;
          v = v > 0.f ? v : expm1f(v);
          int r = mi * 16 + fq * 4 + j;
          IT[r * HFEAT + ((((c >> 3) ^ (r & 7)) << 3) | (c & 7))] = (_Float16)v;
        }
      }
    __syncthreads();
  }

  // ---- final: coalesced read-back from swizzled tile -> global ----
#pragma unroll
  for (int k = 0; k < 8; ++k) {
    int gi = k * 256 + t;
    int r = gi >> 6, g = gi & 63;
    int grow = bm + r;
    if (grow < N_NODES) {
      half8 v = *(const half8*)&IT[r * HFEAT + ((g ^ (r & 7)) << 3)];
      *(half8*)&outp[(size_t)grow * HFEAT + g * 8] = v;
    }
  }
}

// Convert Wh (8 x 512 x 512 f32, K-major) -> frag-major fp16 plane FB:
// FB[((l*16+ks)*32+nf)*512 + lane*8 + j] = Wh[l][(ks*32+fq*8+j)*512 + nf*16+fr]
// (lane = fq*16+fr). One thread per (l,ks,nf,lane) -> 262144 threads.
__global__ __launch_bounds__(256) void convert_fb_kernel(
    const float* __restrict__ Wh, _Float16* __restrict__ FB) {
  int gid = blockIdx.x * 256 + threadIdx.x;   // 1024 blocks
  int l = gid >> 15;
  int rem = gid & 32767;
  int ks = rem >> 11;
  int rem2 = rem & 2047;
  int nf = rem2 >> 6;
  int lane = rem2 & 63;
  int fr = lane & 15, fq = lane >> 4;
  const float* w = Wh + (size_t)l * 512 * 512;
  half8 v;
#pragma unroll
  for (int j = 0; j < 8; ++j)
    v[j] = (_Float16)w[(size_t)(ks * 32 + fq * 8 + j) * 512 + nf * 16 + fr];
  *(half8*)&FB[(size_t)gid * 8] = v;
}

// ---------------------------------------------------------------------------
// Transpose + convert weights: W (KxN fp32) -> WT (NxK fp16), PLAIN layout.
// ---------------------------------------------------------------------------
__global__ __launch_bounds__(256) void convert_wt_kernel(
    const float* __restrict__ W, _Float16* __restrict__ WT, int K, int N) {
  __shared__ float tile[32][33];
  W += (size_t)blockIdx.z * K * N;
  WT += (size_t)blockIdx.z * K * N;
  int k0 = blockIdx.x * 32, n0 = blockIdx.y * 32;
  int t = threadIdx.x;
  int r = t >> 3, c4 = (t & 7) * 4;
  float4 v = *(const float4*)(W + (size_t)(k0 + r) * N + n0 + c4);
  tile[r][c4 + 0] = v.x;
  tile[r][c4 + 1] = v.y;
  tile[r][c4 + 2] = v.z;
  tile[r][c4 + 3] = v.w;
  __syncthreads();
  float x0 = tile[c4 + 0][r], x1 = tile[c4 + 1][r];
  float x2 = tile[c4 + 2][r], x3 = tile[c4 + 3][r];
  size_t o = (size_t)(n0 + r) * K + k0 + c4;
  *(half4*)&WT[o] = (half4){(_Float16)x0, (_Float16)x1, (_Float16)x2, (_Float16)x3};
}

// fp32 -> fp16 plane (for the external node_feat input)
__global__ void convert_f32_f16_kernel(const float* __restrict__ x,
                                       _Float16* __restrict__ y, int n4) {
  int gid = blockIdx.x * blockDim.x + threadIdx.x;
  if (gid >= n4) return;
  float4 v = *(const float4*)(x + gid * 4);
  *(half4*)(y + gid * 4) =
      (half4){(_Float16)v.x, (_Float16)v.y, (_Float16)v.z, (_Float16)v.w};
}

// ---------------------------------------------------------------------------
// CSR build (by dst): histogram -> single-block scan -> scatter.
// ---------------------------------------------------------------------------
__global__ void hist_kernel(const int* __restrict__ dst, int* __restrict__ cnt, int E) {
  int gid = blockIdx.x * blockDim.x + threadIdx.x;
  if (gid < E) atomicAdd(&cnt[dst[gid]], 1);
}

__global__ void scan_kernel(const int* __restrict__ cnt, int* __restrict__ row_ptr,
                            int* __restrict__ cursor, int n) {
  __shared__ int part[256];
  int t = threadIdx.x;
  int chunk = (n + 255) / 256;
  int s0 = t * chunk;
  int s1 = min(s0 + chunk, n);
  int sum = 0;
  for (int i = s0; i < s1; ++i) sum += cnt[i];
  part[t] = sum;
  __syncthreads();
  if (t == 0) {
    int acc = 0;
    for (int i = 0; i < 256; ++i) { int v = part[i]; part[i] = acc; acc += v; }
    row_ptr[n] = acc;
  }
  __syncthreads();
  int run = part[t];
  for (int i = s0; i < s1; ++i) {
    row_ptr[i] = run;
    cursor[i] = run;
    run += cnt[i];
  }
}

__global__ void scatter_kernel(const int* __restrict__ src, const int* __restrict__ dst,
                               int* __restrict__ cursor, int* __restrict__ csr_src,
                               int E) {
  int gid = blockIdx.x * blockDim.x + threadIdx.x;
  if (gid < E) {
    int d = dst[gid];
    int pos = atomicAdd(&cursor[d], 1);
    csr_src[pos] = src[gid];
  }
}

// ---------------------------------------------------------------------------
// GAT pieces (feat fp16 plane; edges in CSR order)
// ---------------------------------------------------------------------------
__global__ __launch_bounds__(256) void el_er_kernel(
    const _Float16* __restrict__ feat, const float* __restrict__ al,
    const float* __restrict__ ar, float* __restrict__ el, float* __restrict__ er) {
  int n = blockIdx.x;
  int t = threadIdx.x;
  int h = t >> 6, lane = t & 63;
  half8 f = *(const half8*)(feat + (size_t)n * HDTOT + h * HD + lane * 8);
  const float* ap = al + h * HD + lane * 8;
  const float* rp = ar + h * HD + lane * 8;
  float4 a0 = *(const float4*)ap, a1 = *(const float4*)(ap + 4);
  float4 r0 = *(const float4*)rp, r1 = *(const float4*)(rp + 4);
  float f0 = (float)f[0], f1 = (float)f[1], f2 = (float)f[2], f3 = (float)f[3];
  float f4 = (float)f[4], f5 = (float)f[5], f6 = (float)f[6], f7 = (float)f[7];
  float sl = f0 * a0.x + f1 * a0.y + f2 * a0.z + f3 * a0.w +
             f4 * a1.x + f5 * a1.y + f6 * a1.z + f7 * a1.w;
  float sr = f0 * r0.x + f1 * r0.y + f2 * r0.z + f3 * r0.w +
             f4 * r1.x + f5 * r1.y + f6 * r1.z + f7 * r1.w;
  for (int off = 32; off; off >>= 1) {
    sl += __shfl_down(sl, off);
    sr += __shfl_down(sr, off);
  }
  if (lane == 0) {
    el[n * NH + h] = sl;
    er[n * NH + h] = sr;
  }
}

// ---------------------------------------------------------------------------
// FUSED per-node edge-softmax + aggregate.
// ---------------------------------------------------------------------------
__global__ __launch_bounds__(256) void softmax_aggregate_kernel(
    const _Float16* __restrict__ feat, const float* __restrict__ el,
    const float* __restrict__ er, const int* __restrict__ row_ptr,
    const int* __restrict__ csr_src, float* __restrict__ e_buf,
    const float* __restrict__ bias, _Float16* __restrict__ out) {
  __shared__ float wl[NH][MAXDEG];
  int n = blockIdx.x;
  int t = threadIdx.x;
  int h = t >> 6, lane = t & 63;
  int s = row_ptr[n], epos = row_ptr[n + 1];
  int deg = epos - s;
  bool lds_w = (deg <= MAXDEG);

  // ---- phase 1: softmax weights ----
  if (deg > 0) {
    float ern = er[n * NH + h];
    if (deg <= 64) {
      int p = s + lane;
      bool on = lane < deg;
      float logit = 0.f;
      float m = -INFINITY;
      if (on) {
        float v = el[csr_src[p] * NH + h] + ern;
        logit = v >= 0.f ? v : 0.2f * v;
        m = logit;
      }
#pragma unroll
      for (int off = 32; off; off >>= 1) m = fmaxf(m, __shfl_xor(m, off));
      float ex = on ? expf(logit - m) : 0.f;
      float sum = ex;
#pragma unroll
      for (int off = 32; off; off >>= 1) sum += __shfl_xor(sum, off);
      float inv = 1.f / sum;
      if (on) wl[h][lane] = ex * inv;
    } else if (lds_w) {
      float m = -INFINITY;
      for (int p = s + lane; p < epos; p += 64) {
        float v = el[csr_src[p] * NH + h] + ern;
        v = v >= 0.f ? v : 0.2f * v;
        wl[h][p - s] = v;
        m = fmaxf(m, v);
      }
      for (int off = 32; off; off >>= 1) m = fmaxf(m, __shfl_xor(m, off));
      float sum = 0.f;
      for (int p = s + lane; p < epos; p += 64) {
        float ex = expf(wl[h][p - s] - m);
        wl[h][p - s] = ex;
        sum += ex;
      }
      for (int off = 32; off; off >>= 1) sum += __shfl_xor(sum, off);
      float inv = 1.f / sum;
      for (int p = s + lane; p < epos; p += 64) wl[h][p - s] *= inv;
    } else {
      float m = -INFINITY;
      for (int p = s + lane; p < epos; p += 64) {
        float v = el[csr_src[p] * NH + h] + ern;
        v = v >= 0.f ? v : 0.2f * v;
        e_buf[p * NH + h] = v;
        m = fmaxf(m, v);
      }
      for (int off = 32; off; off >>= 1) m = fmaxf(m, __shfl_xor(m, off));
      float sum = 0.f;
      for (int p = s + lane; p < epos; p += 64) {
        float ex = expf(e_buf[p * NH + h] - m);
        e_buf[p * NH + h] = ex;
        sum += ex;
      }
      for (int off = 32; off; off >>= 1) sum += __shfl_xor(sum, off);
      float inv = 1.f / sum;
      for (int p = s + lane; p < epos; p += 64) e_buf[p * NH + h] *= inv;
    }
  }
  __syncthreads();

  // ---- phase 2: weighted aggregation (4-deep unroll for MLP) ----
  int base = t * 8;
  float acc[8] = {0.f, 0.f, 0.f, 0.f, 0.f, 0.f, 0.f, 0.f};
  int p = s;
  for (; p + 4 <= epos; p += 4) {
    int q = p - s;
    int sn0 = csr_src[p + 0], sn1 = csr_src[p + 1];
    int sn2 = csr_src[p + 2], sn3 = csr_src[p + 3];
    float a0 = lds_w ? wl[h][q + 0] : e_buf[(p + 0) * NH + h];
    float a1 = lds_w ? wl[h][q + 1] : e_buf[(p + 1) * NH + h];
    float a2 = lds_w ? wl[h][q + 2] : e_buf[(p + 2) * NH + h];
    float a3 = lds_w ? wl[h][q + 3] : e_buf[(p + 3) * NH + h];
    half8 f0 = *(const half8*)(feat + (size_t)sn0 * HDTOT + base);
    half8 f1 = *(const half8*)(feat + (size_t)sn1 * HDTOT + base);
    half8 f2 = *(const half8*)(feat + (size_t)sn2 * HDTOT + base);
    half8 f3 = *(const half8*)(feat + (size_t)sn3 * HDTOT + base);
#pragma unroll
    for (int i = 0; i < 8; ++i)
      acc[i] += a0 * (float)f0[i] + a1 * (float)f1[i] +
                a2 * (float)f2[i] + a3 * (float)f3[i];
  }
  for (; p < epos; ++p) {
    int sn = csr_src[p];
    float a = lds_w ? wl[h][p - s] : e_buf[p * NH + h];
    half8 f = *(const half8*)(feat + (size_t)sn * HDTOT + base);
#pragma unroll
    for (int i = 0; i < 8; ++i) acc[i] += a * (float)f[i];
  }
  float4 b0 = *(const float4*)(bias + base);
  float4 b1 = *(const float4*)(bias + base + 4);
  half8 o;
  o[0] = (_Float16)(acc[0] + b0.x); o[1] = (_Float16)(acc[1] + b0.y);
  o[2] = (_Float16)(acc[2] + b0.z); o[3] = (_Float16)(acc[3] + b0.w);
  o[4] = (_Float16)(acc[4] + b1.x); o[5] = (_Float16)(acc[5] + b1.y);
  o[6] = (_Float16)(acc[6] + b1.z); o[7] = (_Float16)(acc[7] + b1.w);
  *(half8*)(out + (size_t)n * HDTOT + base) = o;
}

// ---------------------------------------------------------------------------
// FUSED pool + BN + Whfc matvec + classifier. One block per graph.
// ---------------------------------------------------------------------------
__global__ __launch_bounds__(512) void pool_final_kernel(
    const _Float16* __restrict__ hfeat, const int* __restrict__ graph_id,
    const float* __restrict__ gamma, const float* __restrict__ beta,
    const float* __restrict__ Whfc, const float* __restrict__ bhfc,
    const float* __restrict__ Wf, const float* __restrict__ bf,
    float* __restrict__ out) {
  __shared__ float sh[HFEAT];
  __shared__ float st[HFEAT];
  __shared__ float r0[8], r1[8];
  __shared__ int s_lo, s_hi;
  int g = blockIdx.x, t = threadIdx.x;
  if (t == 0) {
    int lo = 0, hi = N_NODES;
    while (lo < hi) { int m = (lo + hi) >> 1; if (graph_id[m] < g) lo = m + 1; else hi = m; }
    s_lo = lo;
    int lo2 = lo, hi2 = N_NODES;
    while (lo2 < hi2) { int m = (lo2 + hi2) >> 1; if (graph_id[m] < g + 1) lo2 = m + 1; else hi2 = m; }
    s_hi = lo2;
  }
  __syncthreads();
  int lo = s_lo, hi = s_hi;
  int col = t;  // 512 threads = HFEAT cols
  float acc = 0.f;
  for (int n = lo; n < hi; ++n) acc += (float)hfeat[(size_t)n * HFEAT + col];
  float invc = 1.f / fmaxf((float)(hi - lo), 1.f);
  float bnscale = rsqrtf(1.f + 1e-5f);
  sh[col] = acc * invc * bnscale * gamma[col] + beta[col];
  __syncthreads();
  float a2 = bhfc[col];
  for (int k = 0; k < HFEAT; ++k) a2 += sh[k] * Whfc[k * HFEAT + col];
  st[col] = a2 > 0.f ? a2 : expm1f(a2);
  __syncthreads();
  float p0 = st[col] * Wf[col * 2 + 0];
  float p1 = st[col] * Wf[col * 2 + 1];
  for (int off = 32; off; off >>= 1) {
    p0 += __shfl_down(p0, off);
    p1 += __shfl_down(p1, off);
  }
  int w = t >> 6;
  if ((t & 63) == 0) { r0[w] = p0; r1[w] = p1; }
  __syncthreads();
  if (t == 0) {
    float q0 = bf[0], q1 = bf[1];
#pragma unroll
    for (int i = 0; i < 8; ++i) { q0 += r0[i]; q1 += r1[i]; }
    out[g * 2 + 0] = q0;
    out[g * 2 + 1] = q1;
  }
}

// ---------------------------------------------------------------------------
// Host-side launch
// ---------------------------------------------------------------------------
static void gemm_raw(const _Float16* A, const _Float16* wt, const float* bias,
                     _Float16* C, int M, int N, int K, int act,
                     bool small_m_tile, hipStream_t stream) {
  if (small_m_tile) {
    dim3 grid(N / 128, (M + 63) / 64);
    hipLaunchKernelGGL(gemm_f16_kernel<64>, grid, dim3(256), 0, stream,
                       A, wt, bias, C, M, N, K, act);
  } else {
    dim3 grid(N / 128, (M + 127) / 128);
    hipLaunchKernelGGL(gemm_f16_kernel<128>, grid, dim3(256), 0, stream,
                       A, wt, bias, C, M, N, K, act);
  }
}

static void gemm(const _Float16* A, const float* W, _Float16* wt,
                 const float* bias, _Float16* C, int M, int N, int K, int act,
                 bool small_m_tile, hipStream_t stream) {
  hipLaunchKernelGGL(convert_wt_kernel, dim3(K / 32, N / 32, 1), dim3(256),
                     0, stream, W, wt, K, N);
  gemm_raw(A, wt, bias, C, M, N, K, act, small_m_tile, stream);
}

static void gat_layer(const _Float16* h_in, int K_in, const float* W, _Float16* wt,
                      const float* al, const float* ar, const float* b,
                      const int* row_ptr, const int* csr_src,
                      _Float16* featbuf, float* el, float* er,
                      float* e_buf, _Float16* out, hipStream_t stream) {
  gemm(h_in, W, wt, nullptr, featbuf, N_NODES, HDTOT, K_in, 0, false, stream);
  hipLaunchKernelGGL(el_er_kernel, dim3(N_NODES), dim3(256), 0, stream, featbuf, al, ar, el, er);
  hipLaunchKernelGGL(softmax_aggregate_kernel, dim3(N_NODES), dim3(256), 0, stream,
                     featbuf, el, er, row_ptr, csr_src, e_buf, b, out);
}

extern "C" void kernel_launch(void* const* d_in, const int* in_sizes, int n_in,
                              void* d_out, int out_size, void* d_ws, size_t ws_size,
                              hipStream_t stream) {
  const float* node_feat = (const float*)d_in[0];
  const float* W1 = (const float*)d_in[2];
  const float* al1 = (const float*)d_in[3];
  const float* ar1 = (const float*)d_in[4];
  const float* b1 = (const float*)d_in[5];
  const float* W2 = (const float*)d_in[6];
  const float* al2 = (const float*)d_in[7];
  const float* ar2 = (const float*)d_in[8];
  const float* b2 = (const float*)d_in[9];
  const float* Wfc = (const float*)d_in[10];
  const float* bfc = (const float*)d_in[11];
  const float* Wh = (const float*)d_in[14];
  const float* bh = (const float*)d_in[15];
  const float* gamma = (const float*)d_in[16];
  const float* beta = (const float*)d_in[17];
  const float* Whfc = (const float*)d_in[18];
  const float* bhfc = (const float*)d_in[19];
  const float* Wf = (const float*)d_in[20];
  const float* bf = (const float*)d_in[21];
  const int* src = (const int*)d_in[22];
  const int* dst = (const int*)d_in[23];
  const int* graph_id = (const int*)d_in[24];
  float* out = (float*)d_out;

  // Workspace carve-up
  _Float16* P0 = (_Float16*)d_ws;                 // 10000*2048 fp16
  _Float16* P1 = P0 + (size_t)N_NODES * HDTOT;    // 10000*2048 fp16
  _Float16* Pin = P1 + (size_t)N_NODES * HDTOT;   // 10000*768 fp16
  _Float16* wt = Pin + (size_t)N_NODES * EMB;     // 2048*2048 fp16 (shared)
  _Float16* FB = wt + (size_t)2048 * 2048;        // 8*16*32*512 fp16 = 4 MB
  float* el = (float*)(FB + (size_t)8 * HFEAT * HFEAT);
  float* er = el + N_NODES * NH;
  float* e_buf = er + N_NODES * NH;       // N_EDGES*NH (fallback scratch)
  int* cnt = (int*)(e_buf + (size_t)N_EDGES * NH);
  int* row_ptr = cnt + N_NODES;           // N_NODES+1
  int* cursor = row_ptr + N_NODES + 1;
  int* csr_src = cursor + N_NODES;        // N_EDGES

  // --- CSR build (by dst), once per launch ---
  hipMemsetAsync(cnt, 0, N_NODES * sizeof(int), stream);
  hipLaunchKernelGGL(hist_kernel, dim3((N_EDGES + 255) / 256), dim3(256), 0, stream,
                     dst, cnt, N_EDGES);
  hipLaunchKernelGGL(scan_kernel, dim3(1), dim3(256), 0, stream, cnt, row_ptr, cursor, N_NODES);
  hipLaunchKernelGGL(scatter_kernel, dim3((N_EDGES + 255) / 256), dim3(256), 0, stream,
                     src, dst, cursor, csr_src, N_EDGES);

  // --- node_feat -> fp16 plane; hidden weights -> frag-major fp16 ---
  int n4 = N_NODES * EMB / 4;
  hipLaunchKernelGGL(convert_f32_f16_kernel, dim3((n4 + 255) / 256), dim3(256), 0, stream,
                     node_feat, Pin, n4);
  hipLaunchKernelGGL(convert_fb_kernel, dim3(1024), dim3(256), 0, stream, Wh, FB);

  // --- GAT layer 1: Pin(768) -> feat P0 -> h1 P1 (2048) ---
  gat_layer(Pin, EMB, W1, wt, al1, ar1, b1, row_ptr, csr_src,
            P0, el, er, e_buf, P1, stream);
  // --- GAT layer 2: P1(2048) -> feat P0 -> h2 P1 (2048) ---
  gat_layer(P1, HDTOT, W2, wt, al2, ar2, b2, row_ptr, csr_src,
            P0, el, er, e_buf, P1, stream);

  // --- h = elu(P1 @ Wfc + bfc) -> P0 (N x 512) ---
  gemm(P1, Wfc, wt, bfc, P0, N_NODES, HFEAT, HDTOT, 1, true, stream);

  // --- 8 hidden layers: ONE fused kernel, activations resident in LDS ---
  hipLaunchKernelGGL(hidden8_kernel, dim3((N_NODES + HB - 1) / HB), dim3(256),
                     0, stream, P0, FB, bh, P1);

  // --- fused mean-pool + BN + fc + classifier ---
  hipLaunchKernelGGL(pool_final_kernel, dim3(N_GRAPHS), dim3(512), 0, stream,
                     P1, graph_id, gamma, beta, Whfc, bhfc, Wf, bf, out);
}

// Round 4
// 716.839 us; speedup vs baseline: 1.1926x; 1.1926x over previous
//
#include <hip/hip_runtime.h>
#include <hip/hip_cooperative_groups.h>
#include <hip/hip_bf16.h>
#include <math.h>

namespace cg = cooperative_groups;

// Problem constants (from reference)
#define N_NODES 10000
#define N_EDGES 80000
#define N_GRAPHS 64
#define NH 4
#define HD 512
#define HDTOT 2048   // NH*HD
#define EMB 768
#define HFEAT 512
#define MAXDEG 512   // LDS softmax-weight capacity per node

typedef _Float16 half8 __attribute__((ext_vector_type(8)));
typedef _Float16 half4 __attribute__((ext_vector_type(4)));
typedef float f32x4 __attribute__((ext_vector_type(4)));

// Async global->LDS, 16B per lane. LDS dest = wave-uniform base + lane*16;
// the GLOBAL SOURCE ADDRESS IS PER-LANE. Lanes fetch their row's K-granules
// in XOR-permuted order, so the DMA lands a swizzled LDS image from a PLAIN
// row-major global plane. Zero VALU repack.
__device__ __forceinline__ void gload_lds16(const void* g, void* l) {
  __builtin_amdgcn_global_load_lds(
      (const __attribute__((address_space(1))) unsigned int*)g,
      (__attribute__((address_space(3))) unsigned int*)l, 16, 0, 0);
}

// ---------------------------------------------------------------------------
// Plain-fp16 MFMA GEMM (m97-structure): C = act(A @ B + bias), fp16 planes.
// R2 post-mortem: 256^2 counted-vmcnt pipeline = 697 TF at full machine vs
// this kernel's 763 -> fc GEMMs stay on this proven path.
// R3 post-mortem: block-fused hidden8 = 78 TF (per-wave L2 B-streaming,
// no sharing; occupancy 7%) -> hidden chain reverted to this tile body,
// launch overhead attacked via the cooperative chain kernel below instead.
// Tile BM x 128, 256 threads. K%64==0.
// ---------------------------------------------------------------------------
template <int BM>
__global__ __launch_bounds__(256) void gemm_f16_kernel(
    const _Float16* __restrict__ A, const _Float16* __restrict__ BT,
    const float* __restrict__ bias, _Float16* __restrict__ C,
    int M, int N, int K, int act) {
  constexpr int WR = (BM == 128) ? 2 : 1;  // wave grid rows
  constexpr int WC = 4 / WR;               // wave grid cols
  constexpr int MI = (BM / WR) / 16;       // m-frags per wave (4)
  constexpr int NI = (128 / WC) / 16;      // n-frags per wave (4 or 2)
  constexpr int NW = NI * 16;              // wave n-width (64 or 32)
  constexpr int CS = NW + 4;               // epilogue scratch row stride
  constexpr int GPR = NW / 8;              // 16B granules per scratch row

  __shared__ _Float16 smem[(BM + 128) * 64];
  _Float16* As = smem;             // BM x 64 (swizzled image)
  _Float16* Bs = smem + BM * 64;   // 128 x 64 (swizzled image)

  const int bn = blockIdx.x * 128, bm = blockIdx.y * BM;
  const int t = threadIdx.x;
  const int lane = t & 63, wave = t >> 6;
  const int wr = wave / WC, wc = wave % WC;
  const int m0 = wr * (BM / WR), n0 = wc * NW;
  const int fr = lane & 15, fq = lane >> 4;

  f32x4 acc[MI][NI];
#pragma unroll
  for (int i = 0; i < MI; ++i)
#pragma unroll
    for (int j = 0; j < NI; ++j) acc[i][j] = (f32x4){0.f, 0.f, 0.f, 0.f};

  for (int k0 = 0; k0 < K; k0 += 64) {
    __syncthreads();  // protect LDS from previous iteration's readers
#pragma unroll
    for (int it = 0; it < BM / 32; ++it) {
      int gid = it * 256 + t;
      int r = gid >> 3;
      int q = (gid & 7) ^ (r & 7);  // fetch permuted granule
      int grow = bm + r;
      if (grow >= M) grow = M - 1;  // clamp; garbage masked in epilogue
      gload_lds16(A + (size_t)grow * K + k0 + q * 8,
                  &As[(it * 256 + wave * 64) * 8]);
    }
#pragma unroll
    for (int it = 0; it < 4; ++it) {
      int gid = it * 256 + t;
      int r = gid >> 3;
      int q = (gid & 7) ^ (r & 7);
      gload_lds16(BT + (size_t)(bn + r) * K + k0 + q * 8,
                  &Bs[(it * 256 + wave * 64) * 8]);
    }
    __syncthreads();

#pragma unroll
    for (int kk = 0; kk < 2; ++kk) {
      half8 af[MI], bf[NI];
#pragma unroll
      for (int mi = 0; mi < MI; ++mi) {
        int m = m0 + mi * 16 + fr;
        af[mi] = *(const half8*)&As[m * 64 + (((kk * 4 + fq) ^ (m & 7))) * 8];
      }
#pragma unroll
      for (int ni = 0; ni < NI; ++ni) {
        int n = n0 + ni * 16 + fr;
        bf[ni] = *(const half8*)&Bs[n * 64 + (((kk * 4 + fq) ^ (n & 7))) * 8];
      }
#pragma unroll
      for (int mi = 0; mi < MI; ++mi)
#pragma unroll
        for (int ni = 0; ni < NI; ++ni)
          acc[mi][ni] = __builtin_amdgcn_mfma_f32_16x16x32_f16(
              af[mi], bf[ni], acc[mi][ni], 0, 0, 0);
    }
  }
  __syncthreads();  // all K-loop LDS reads done; staging smem reusable
  _Float16* cs = smem + wave * 16 * CS;  // wave-private scratch (16 x CS)
#pragma unroll
  for (int mi = 0; mi < MI; ++mi) {
#pragma unroll
    for (int ni = 0; ni < NI; ++ni) {
      float bb = bias ? bias[bn + n0 + ni * 16 + fr] : 0.f;
#pragma unroll
      for (int j = 0; j < 4; ++j) {
        float v = acc[mi][ni][j] + bb;
        if (act == 1) v = v > 0.f ? v : expm1f(v);
        cs[(fq * 4 + j) * CS + ni * 16 + fr] = (_Float16)v;
      }
    }
#pragma unroll
    for (int i = 0; i < NW / 32; ++i) {
      int piece = i * 64 + lane;
      int r = piece / GPR, g = piece % GPR;
      int grow = bm + m0 + mi * 16 + r;
      if (grow < M) {
        half8 v = *(const half8*)&cs[r * CS + g * 8];
        *(half8*)&C[(size_t)grow * N + bn + n0 + g * 8] = v;
      }
    }
  }
}

// ---------------------------------------------------------------------------
// NEW (R4): cooperative 8-layer hidden chain. EXACT gemm<64> tile body
// (identical FP order -> identical numerics), one 64x128 tile per block per
// layer (grid = 157*4 = 628 blocks), cg::this_grid().sync() between layers.
// Removes 7 launch boundaries and keeps the 10 MB activations L2/L3-hot.
// Parallelism is unchanged vs the 8-launch chain (R3's lost-occupancy trap
// avoided: B is still LDS-staged and shared by all 4 waves of the block).
// Co-residency: 24 KB LDS (6 blocks/CU), ~90 VGPR (~5 blocks/CU) >> the
// 2.45 blocks/CU required; guarded at runtime by an occupancy query with
// fallback to 8 plain launches.
// ---------------------------------------------------------------------------
__global__ __launch_bounds__(256) void hidden_chain_coop(
    _Float16* __restrict__ b0, _Float16* __restrict__ b1,
    const _Float16* __restrict__ whh, const float* __restrict__ bh) {
  constexpr int MI = 4, NI = 2, NW = 32, CS = 36;
  __shared__ _Float16 smem[(64 + 128) * 64];  // 24 KB
  _Float16* As = smem;
  _Float16* Bs = smem + 64 * 64;

  const int tile = blockIdx.x;
  const int bn = (tile & 3) * 128;   // 4 col-blocks of 128 (N=512)
  const int bm = (tile >> 2) * 64;   // 157 row-blocks of 64
  const int t = threadIdx.x;
  const int lane = t & 63, wave = t >> 6;
  const int n0 = wave * NW;          // WR=1, WC=4
  const int fr = lane & 15, fq = lane >> 4;

  for (int l = 0; l < 8; ++l) {
    const _Float16* A = (l & 1) ? b1 : b0;
    _Float16* C = (l & 1) ? b0 : b1;           // l=7 writes b0 (=P0)
    const _Float16* BT = whh + (size_t)l * (HFEAT * HFEAT);
    const float* bias = bh + l * HFEAT;

    f32x4 acc[MI][NI];
#pragma unroll
    for (int i = 0; i < MI; ++i)
#pragma unroll
      for (int j = 0; j < NI; ++j) acc[i][j] = (f32x4){0.f, 0.f, 0.f, 0.f};

    for (int k0 = 0; k0 < HFEAT; k0 += 64) {
      __syncthreads();
#pragma unroll
      for (int it = 0; it < 2; ++it) {  // stage A: 64 x 64
        int gid = it * 256 + t;
        int r = gid >> 3;
        int q = (gid & 7) ^ (r & 7);
        int grow = bm + r;
        if (grow >= N_NODES) grow = N_NODES - 1;
        gload_lds16(A + (size_t)grow * HFEAT + k0 + q * 8,
                    &As[(it * 256 + wave * 64) * 8]);
      }
#pragma unroll
      for (int it = 0; it < 4; ++it) {  // stage B: 128 x 64
        int gid = it * 256 + t;
        int r = gid >> 3;
        int q = (gid & 7) ^ (r & 7);
        gload_lds16(BT + (size_t)(bn + r) * HFEAT + k0 + q * 8,
                    &Bs[(it * 256 + wave * 64) * 8]);
      }
      __syncthreads();

#pragma unroll
      for (int kk = 0; kk < 2; ++kk) {
        half8 af[MI], bf[NI];
#pragma unroll
        for (int mi = 0; mi < MI; ++mi) {
          int m = mi * 16 + fr;
          af[mi] = *(const half8*)&As[m * 64 + (((kk * 4 + fq) ^ (m & 7))) * 8];
        }
#pragma unroll
        for (int ni = 0; ni < NI; ++ni) {
          int n = n0 + ni * 16 + fr;
          bf[ni] = *(const half8*)&Bs[n * 64 + (((kk * 4 + fq) ^ (n & 7))) * 8];
        }
#pragma unroll
        for (int mi = 0; mi < MI; ++mi)
#pragma unroll
          for (int ni = 0; ni < NI; ++ni)
            acc[mi][ni] = __builtin_amdgcn_mfma_f32_16x16x32_f16(
                af[mi], bf[ni], acc[mi][ni], 0, 0, 0);
      }
    }
    __syncthreads();  // all K-loop LDS reads done; smem reusable as scratch

    _Float16* cs = smem + wave * 16 * CS;  // wave-private (16 x 36)
#pragma unroll
    for (int mi = 0; mi < MI; ++mi) {
#pragma unroll
      for (int ni = 0; ni < NI; ++ni) {
        float bb = bias[bn + n0 + ni * 16 + fr];
#pragma unroll
        for (int j = 0; j < 4; ++j) {
          float v = acc[mi][ni][j] + bb;
          v = v > 0.f ? v : expm1f(v);  // ELU
          cs[(fq * 4 + j) * CS + ni * 16 + fr] = (_Float16)v;
        }
      }
      {
        int r = lane >> 2, g = lane & 3;
        int grow = bm + mi * 16 + r;
        if (grow < N_NODES) {
          half8 v = *(const half8*)&cs[r * CS + g * 8];
          *(half8*)&C[(size_t)grow * HFEAT + bn + n0 + g * 8] = v;
        }
      }
    }

    if (l < 7) {
      __threadfence();          // make C-writes visible device-wide
      cg::this_grid().sync();   // all blocks done with layer l
    }
  }
}

// ---------------------------------------------------------------------------
// Transpose + convert weights: W (KxN fp32) -> WT (NxK fp16), PLAIN layout.
// blockIdx.z batches matrices (stride K*N).
// ---------------------------------------------------------------------------
__global__ __launch_bounds__(256) void convert_wt_kernel(
    const float* __restrict__ W, _Float16* __restrict__ WT, int K, int N) {
  __shared__ float tile[32][33];
  W += (size_t)blockIdx.z * K * N;
  WT += (size_t)blockIdx.z * K * N;
  int k0 = blockIdx.x * 32, n0 = blockIdx.y * 32;
  int t = threadIdx.x;
  int r = t >> 3, c4 = (t & 7) * 4;
  float4 v = *(const float4*)(W + (size_t)(k0 + r) * N + n0 + c4);
  tile[r][c4 + 0] = v.x;
  tile[r][c4 + 1] = v.y;
  tile[r][c4 + 2] = v.z;
  tile[r][c4 + 3] = v.w;
  __syncthreads();
  float x0 = tile[c4 + 0][r], x1 = tile[c4 + 1][r];
  float x2 = tile[c4 + 2][r], x3 = tile[c4 + 3][r];
  size_t o = (size_t)(n0 + r) * K + k0 + c4;
  *(half4*)&WT[o] = (half4){(_Float16)x0, (_Float16)x1, (_Float16)x2, (_Float16)x3};
}

// fp32 -> fp16 plane (for the external node_feat input)
__global__ void convert_f32_f16_kernel(const float* __restrict__ x,
                                       _Float16* __restrict__ y, int n4) {
  int gid = blockIdx.x * blockDim.x + threadIdx.x;
  if (gid >= n4) return;
  float4 v = *(const float4*)(x + gid * 4);
  *(half4*)(y + gid * 4) =
      (half4){(_Float16)v.x, (_Float16)v.y, (_Float16)v.z, (_Float16)v.w};
}

// ---------------------------------------------------------------------------
// CSR build (by dst): histogram -> single-block scan -> scatter.
// ---------------------------------------------------------------------------
__global__ void hist_kernel(const int* __restrict__ dst, int* __restrict__ cnt, int E) {
  int gid = blockIdx.x * blockDim.x + threadIdx.x;
  if (gid < E) atomicAdd(&cnt[dst[gid]], 1);
}

__global__ void scan_kernel(const int* __restrict__ cnt, int* __restrict__ row_ptr,
                            int* __restrict__ cursor, int n) {
  __shared__ int part[256];
  int t = threadIdx.x;
  int chunk = (n + 255) / 256;
  int s0 = t * chunk;
  int s1 = min(s0 + chunk, n);
  int sum = 0;
  for (int i = s0; i < s1; ++i) sum += cnt[i];
  part[t] = sum;
  __syncthreads();
  if (t == 0) {
    int acc = 0;
    for (int i = 0; i < 256; ++i) { int v = part[i]; part[i] = acc; acc += v; }
    row_ptr[n] = acc;
  }
  __syncthreads();
  int run = part[t];
  for (int i = s0; i < s1; ++i) {
    row_ptr[i] = run;
    cursor[i] = run;
    run += cnt[i];
  }
}

__global__ void scatter_kernel(const int* __restrict__ src, const int* __restrict__ dst,
                               int* __restrict__ cursor, int* __restrict__ csr_src,
                               int E) {
  int gid = blockIdx.x * blockDim.x + threadIdx.x;
  if (gid < E) {
    int d = dst[gid];
    int pos = atomicAdd(&cursor[d], 1);
    csr_src[pos] = src[gid];
  }
}

// ---------------------------------------------------------------------------
// GAT pieces (feat fp16 plane; edges in CSR order)
// ---------------------------------------------------------------------------
__global__ __launch_bounds__(256) void el_er_kernel(
    const _Float16* __restrict__ feat, const float* __restrict__ al,
    const float* __restrict__ ar, float* __restrict__ el, float* __restrict__ er) {
  int n = blockIdx.x;
  int t = threadIdx.x;
  int h = t >> 6, lane = t & 63;
  half8 f = *(const half8*)(feat + (size_t)n * HDTOT + h * HD + lane * 8);
  const float* ap = al + h * HD + lane * 8;
  const float* rp = ar + h * HD + lane * 8;
  float4 a0 = *(const float4*)ap, a1 = *(const float4*)(ap + 4);
  float4 r0 = *(const float4*)rp, r1 = *(const float4*)(rp + 4);
  float f0 = (float)f[0], f1 = (float)f[1], f2 = (float)f[2], f3 = (float)f[3];
  float f4 = (float)f[4], f5 = (float)f[5], f6 = (float)f[6], f7 = (float)f[7];
  float sl = f0 * a0.x + f1 * a0.y + f2 * a0.z + f3 * a0.w +
             f4 * a1.x + f5 * a1.y + f6 * a1.z + f7 * a1.w;
  float sr = f0 * r0.x + f1 * r0.y + f2 * r0.z + f3 * r0.w +
             f4 * r1.x + f5 * r1.y + f6 * r1.z + f7 * r1.w;
  for (int off = 32; off; off >>= 1) {
    sl += __shfl_down(sl, off);
    sr += __shfl_down(sr, off);
  }
  if (lane == 0) {
    el[n * NH + h] = sl;
    er[n * NH + h] = sr;
  }
}

// ---------------------------------------------------------------------------
// FUSED per-node edge-softmax + aggregate.
// ---------------------------------------------------------------------------
__global__ __launch_bounds__(256) void softmax_aggregate_kernel(
    const _Float16* __restrict__ feat, const float* __restrict__ el,
    const float* __restrict__ er, const int* __restrict__ row_ptr,
    const int* __restrict__ csr_src, float* __restrict__ e_buf,
    const float* __restrict__ bias, _Float16* __restrict__ out) {
  __shared__ float wl[NH][MAXDEG];
  int n = blockIdx.x;
  int t = threadIdx.x;
  int h = t >> 6, lane = t & 63;
  int s = row_ptr[n], epos = row_ptr[n + 1];
  int deg = epos - s;
  bool lds_w = (deg <= MAXDEG);

  // ---- phase 1: softmax weights ----
  if (deg > 0) {
    float ern = er[n * NH + h];
    if (deg <= 64) {
      int p = s + lane;
      bool on = lane < deg;
      float logit = 0.f;
      float m = -INFINITY;
      if (on) {
        float v = el[csr_src[p] * NH + h] + ern;
        logit = v >= 0.f ? v : 0.2f * v;
        m = logit;
      }
#pragma unroll
      for (int off = 32; off; off >>= 1) m = fmaxf(m, __shfl_xor(m, off));
      float ex = on ? expf(logit - m) : 0.f;
      float sum = ex;
#pragma unroll
      for (int off = 32; off; off >>= 1) sum += __shfl_xor(sum, off);
      float inv = 1.f / sum;
      if (on) wl[h][lane] = ex * inv;
    } else if (lds_w) {
      float m = -INFINITY;
      for (int p = s + lane; p < epos; p += 64) {
        float v = el[csr_src[p] * NH + h] + ern;
        v = v >= 0.f ? v : 0.2f * v;
        wl[h][p - s] = v;
        m = fmaxf(m, v);
      }
      for (int off = 32; off; off >>= 1) m = fmaxf(m, __shfl_xor(m, off));
      float sum = 0.f;
      for (int p = s + lane; p < epos; p += 64) {
        float ex = expf(wl[h][p - s] - m);
        wl[h][p - s] = ex;
        sum += ex;
      }
      for (int off = 32; off; off >>= 1) sum += __shfl_xor(sum, off);
      float inv = 1.f / sum;
      for (int p = s + lane; p < epos; p += 64) wl[h][p - s] *= inv;
    } else {
      float m = -INFINITY;
      for (int p = s + lane; p < epos; p += 64) {
        float v = el[csr_src[p] * NH + h] + ern;
        v = v >= 0.f ? v : 0.2f * v;
        e_buf[p * NH + h] = v;
        m = fmaxf(m, v);
      }
      for (int off = 32; off; off >>= 1) m = fmaxf(m, __shfl_xor(m, off));
      float sum = 0.f;
      for (int p = s + lane; p < epos; p += 64) {
        float ex = expf(e_buf[p * NH + h] - m);
        e_buf[p * NH + h] = ex;
        sum += ex;
      }
      for (int off = 32; off; off >>= 1) sum += __shfl_xor(sum, off);
      float inv = 1.f / sum;
      for (int p = s + lane; p < epos; p += 64) e_buf[p * NH + h] *= inv;
    }
  }
  __syncthreads();

  // ---- phase 2: weighted aggregation (4-deep unroll for MLP) ----
  int base = t * 8;
  float acc[8] = {0.f, 0.f, 0.f, 0.f, 0.f, 0.f, 0.f, 0.f};
  int p = s;
  for (; p + 4 <= epos; p += 4) {
    int q = p - s;
    int sn0 = csr_src[p + 0], sn1 = csr_src[p + 1];
    int sn2 = csr_src[p + 2], sn3 = csr_src[p + 3];
    float a0 = lds_w ? wl[h][q + 0] : e_buf[(p + 0) * NH + h];
    float a1 = lds_w ? wl[h][q + 1] : e_buf[(p + 1) * NH + h];
    float a2 = lds_w ? wl[h][q + 2] : e_buf[(p + 2) * NH + h];
    float a3 = lds_w ? wl[h][q + 3] : e_buf[(p + 3) * NH + h];
    half8 f0 = *(const half8*)(feat + (size_t)sn0 * HDTOT + base);
    half8 f1 = *(const half8*)(feat + (size_t)sn1 * HDTOT + base);
    half8 f2 = *(const half8*)(feat + (size_t)sn2 * HDTOT + base);
    half8 f3 = *(const half8*)(feat + (size_t)sn3 * HDTOT + base);
#pragma unroll
    for (int i = 0; i < 8; ++i)
      acc[i] += a0 * (float)f0[i] + a1 * (float)f1[i] +
                a2 * (float)f2[i] + a3 * (float)f3[i];
  }
  for (; p < epos; ++p) {
    int sn = csr_src[p];
    float a = lds_w ? wl[h][p - s] : e_buf[p * NH + h];
    half8 f = *(const half8*)(feat + (size_t)sn * HDTOT + base);
#pragma unroll
    for (int i = 0; i < 8; ++i) acc[i] += a * (float)f[i];
  }
  float4 b0 = *(const float4*)(bias + base);
  float4 b1 = *(const float4*)(bias + base + 4);
  half8 o;
  o[0] = (_Float16)(acc[0] + b0.x); o[1] = (_Float16)(acc[1] + b0.y);
  o[2] = (_Float16)(acc[2] + b0.z); o[3] = (_Float16)(acc[3] + b0.w);
  o[4] = (_Float16)(acc[4] + b1.x); o[5] = (_Float16)(acc[5] + b1.y);
  o[6] = (_Float16)(acc[6] + b1.z); o[7] = (_Float16)(acc[7] + b1.w);
  *(half8*)(out + (size_t)n * HDTOT + base) = o;
}

// ---------------------------------------------------------------------------
// FUSED pool + BN + Whfc matvec + classifier. One block per graph.
// ---------------------------------------------------------------------------
__global__ __launch_bounds__(512) void pool_final_kernel(
    const _Float16* __restrict__ hfeat, const int* __restrict__ graph_id,
    const float* __restrict__ gamma, const float* __restrict__ beta,
    const float* __restrict__ Whfc, const float* __restrict__ bhfc,
    const float* __restrict__ Wf, const float* __restrict__ bf,
    float* __restrict__ out) {
  __shared__ float sh[HFEAT];
  __shared__ float st[HFEAT];
  __shared__ float r0[8], r1[8];
  __shared__ int s_lo, s_hi;
  int g = blockIdx.x, t = threadIdx.x;
  if (t == 0) {
    int lo = 0, hi = N_NODES;
    while (lo < hi) { int m = (lo + hi) >> 1; if (graph_id[m] < g) lo = m + 1; else hi = m; }
    s_lo = lo;
    int lo2 = lo, hi2 = N_NODES;
    while (lo2 < hi2) { int m = (lo2 + hi2) >> 1; if (graph_id[m] < g + 1) lo2 = m + 1; else hi2 = m; }
    s_hi = lo2;
  }
  __syncthreads();
  int lo = s_lo, hi = s_hi;
  int col = t;  // 512 threads = HFEAT cols
  float acc = 0.f;
  for (int n = lo; n < hi; ++n) acc += (float)hfeat[(size_t)n * HFEAT + col];
  float invc = 1.f / fmaxf((float)(hi - lo), 1.f);
  float bnscale = rsqrtf(1.f + 1e-5f);
  sh[col] = acc * invc * bnscale * gamma[col] + beta[col];
  __syncthreads();
  float a2 = bhfc[col];
  for (int k = 0; k < HFEAT; ++k) a2 += sh[k] * Whfc[k * HFEAT + col];
  st[col] = a2 > 0.f ? a2 : expm1f(a2);
  __syncthreads();
  float p0 = st[col] * Wf[col * 2 + 0];
  float p1 = st[col] * Wf[col * 2 + 1];
  for (int off = 32; off; off >>= 1) {
    p0 += __shfl_down(p0, off);
    p1 += __shfl_down(p1, off);
  }
  int w = t >> 6;
  if ((t & 63) == 0) { r0[w] = p0; r1[w] = p1; }
  __syncthreads();
  if (t == 0) {
    float q0 = bf[0], q1 = bf[1];
#pragma unroll
    for (int i = 0; i < 8; ++i) { q0 += r0[i]; q1 += r1[i]; }
    out[g * 2 + 0] = q0;
    out[g * 2 + 1] = q1;
  }
}

// ---------------------------------------------------------------------------
// Host-side launch
// ---------------------------------------------------------------------------
static void gemm_raw(const _Float16* A, const _Float16* wt, const float* bias,
                     _Float16* C, int M, int N, int K, int act,
                     bool small_m_tile, hipStream_t stream) {
  if (small_m_tile) {
    dim3 grid(N / 128, (M + 63) / 64);
    hipLaunchKernelGGL(gemm_f16_kernel<64>, grid, dim3(256), 0, stream,
                       A, wt, bias, C, M, N, K, act);
  } else {
    dim3 grid(N / 128, (M + 127) / 128);
    hipLaunchKernelGGL(gemm_f16_kernel<128>, grid, dim3(256), 0, stream,
                       A, wt, bias, C, M, N, K, act);
  }
}

static void gemm(const _Float16* A, const float* W, _Float16* wt,
                 const float* bias, _Float16* C, int M, int N, int K, int act,
                 bool small_m_tile, hipStream_t stream) {
  hipLaunchKernelGGL(convert_wt_kernel, dim3(K / 32, N / 32, 1), dim3(256),
                     0, stream, W, wt, K, N);
  gemm_raw(A, wt, bias, C, M, N, K, act, small_m_tile, stream);
}

static void gat_layer(const _Float16* h_in, int K_in, const float* W, _Float16* wt,
                      const float* al, const float* ar, const float* b,
                      const int* row_ptr, const int* csr_src,
                      _Float16* featbuf, float* el, float* er,
                      float* e_buf, _Float16* out, hipStream_t stream) {
  gemm(h_in, W, wt, nullptr, featbuf, N_NODES, HDTOT, K_in, 0, false, stream);
  hipLaunchKernelGGL(el_er_kernel, dim3(N_NODES), dim3(256), 0, stream, featbuf, al, ar, el, er);
  hipLaunchKernelGGL(softmax_aggregate_kernel, dim3(N_NODES), dim3(256), 0, stream,
                     featbuf, el, er, row_ptr, csr_src, e_buf, b, out);
}

// Guard: cooperative launch needs all 628 blocks co-resident. Host-only query,
// capture-safe. Fallback: 8 chained plain launches (identical numerics).
static bool hidden_coop_ok() {
  static int cached = -1;
  if (cached < 0) {
    int maxb = 0;
    hipError_t e = hipOccupancyMaxActiveBlocksPerMultiprocessor(
        &maxb, hidden_chain_coop, 256, 0);
    cached = (e == hipSuccess && maxb >= 3) ? 1 : 0;  // 3*256 CUs = 768 >= 628
  }
  return cached == 1;
}

extern "C" void kernel_launch(void* const* d_in, const int* in_sizes, int n_in,
                              void* d_out, int out_size, void* d_ws, size_t ws_size,
                              hipStream_t stream) {
  const float* node_feat = (const float*)d_in[0];
  const float* W1 = (const float*)d_in[2];
  const float* al1 = (const float*)d_in[3];
  const float* ar1 = (const float*)d_in[4];
  const float* b1 = (const float*)d_in[5];
  const float* W2 = (const float*)d_in[6];
  const float* al2 = (const float*)d_in[7];
  const float* ar2 = (const float*)d_in[8];
  const float* b2 = (const float*)d_in[9];
  const float* Wfc = (const float*)d_in[10];
  const float* bfc = (const float*)d_in[11];
  const float* Wh = (const float*)d_in[14];
  const float* bh = (const float*)d_in[15];
  const float* gamma = (const float*)d_in[16];
  const float* beta = (const float*)d_in[17];
  const float* Whfc = (const float*)d_in[18];
  const float* bhfc = (const float*)d_in[19];
  const float* Wf = (const float*)d_in[20];
  const float* bf = (const float*)d_in[21];
  const int* src = (const int*)d_in[22];
  const int* dst = (const int*)d_in[23];
  const int* graph_id = (const int*)d_in[24];
  float* out = (float*)d_out;

  // Workspace carve-up
  _Float16* P0 = (_Float16*)d_ws;                 // 10000*2048 fp16
  _Float16* P1 = P0 + (size_t)N_NODES * HDTOT;    // 10000*2048 fp16
  _Float16* Pin = P1 + (size_t)N_NODES * HDTOT;   // 10000*768 fp16
  _Float16* wt = Pin + (size_t)N_NODES * EMB;     // 2048*2048 fp16 (shared)
  _Float16* whh = wt + (size_t)2048 * 2048;       // 8*512*512 fp16 (hidden)
  float* el = (float*)(whh + (size_t)8 * HFEAT * HFEAT);
  float* er = el + N_NODES * NH;
  float* e_buf = er + N_NODES * NH;       // N_EDGES*NH (fallback scratch)
  int* cnt = (int*)(e_buf + (size_t)N_EDGES * NH);
  int* row_ptr = cnt + N_NODES;           // N_NODES+1
  int* cursor = row_ptr + N_NODES + 1;
  int* csr_src = cursor + N_NODES;        // N_EDGES

  // --- CSR build (by dst), once per launch ---
  hipMemsetAsync(cnt, 0, N_NODES * sizeof(int), stream);
  hipLaunchKernelGGL(hist_kernel, dim3((N_EDGES + 255) / 256), dim3(256), 0, stream,
                     dst, cnt, N_EDGES);
  hipLaunchKernelGGL(scan_kernel, dim3(1), dim3(256), 0, stream, cnt, row_ptr, cursor, N_NODES);
  hipLaunchKernelGGL(scatter_kernel, dim3((N_EDGES + 255) / 256), dim3(256), 0, stream,
                     src, dst, cursor, csr_src, N_EDGES);

  // --- node_feat -> fp16 plane; hidden weights -> transposed fp16 (batched) ---
  int n4 = N_NODES * EMB / 4;
  hipLaunchKernelGGL(convert_f32_f16_kernel, dim3((n4 + 255) / 256), dim3(256), 0, stream,
                     node_feat, Pin, n4);
  hipLaunchKernelGGL(convert_wt_kernel, dim3(HFEAT / 32, HFEAT / 32, 8),
                     dim3(256), 0, stream, Wh, whh, HFEAT, HFEAT);

  // --- GAT layer 1: Pin(768) -> feat P0 -> h1 P1 (2048) ---
  gat_layer(Pin, EMB, W1, wt, al1, ar1, b1, row_ptr, csr_src,
            P0, el, er, e_buf, P1, stream);
  // --- GAT layer 2: P1(2048) -> feat P0 -> h2 P1 (2048) ---
  gat_layer(P1, HDTOT, W2, wt, al2, ar2, b2, row_ptr, csr_src,
            P0, el, er, e_buf, P1, stream);

  // --- h = elu(P1 @ Wfc + bfc) -> P0 (N x 512) ---
  gemm(P1, Wfc, wt, bfc, P0, N_NODES, HFEAT, HDTOT, 1, true, stream);

  // --- 8 hidden layers: cooperative chain (l7 writes P0), else fallback ---
  if (hidden_coop_ok()) {
    _Float16* a0 = P0;
    _Float16* a1 = P1;
    const _Float16* wp = whh;
    const float* bp = bh;
    void* args[] = {&a0, &a1, &wp, &bp};
    hipLaunchCooperativeKernel((const void*)hidden_chain_coop, dim3(628),
                               dim3(256), args, 0, stream);
  } else {
    _Float16* cur = P0;
    _Float16* nxt = P1;
    for (int i = 0; i < 8; ++i) {
      gemm_raw(cur, whh + (size_t)i * HFEAT * HFEAT, bh + (size_t)i * HFEAT,
               nxt, N_NODES, HFEAT, HFEAT, 1, true, stream);
      _Float16* tmp = cur; cur = nxt; nxt = tmp;
    }
    // after 8 swaps, cur == P0 holds the final h
  }

  // --- fused mean-pool + BN + fc + classifier ---
  hipLaunchKernelGGL(pool_final_kernel, dim3(N_GRAPHS), dim3(512), 0, stream,
                     P0, graph_id, gamma, beta, Whfc, bhfc, Wf, bf, out);
}